// Round 6
// baseline (118.883 us; speedup 1.0000x reference)
//
#include <hip/hip_runtime.h>
#include <hip/hip_bf16.h>

// ECE over logits (8,19,512,1024) f32, labels (8,512,1024) int32.
// R6 = R5 with the fatal indexing bug fixed: group k of a thread's 16 pixels is
//     at plane offset rem + 4*k (NOT 16*k, which read wrong pixels and ran 35
//     floats past the buffer end -> GPU memory fault -> core dump in R5).
//     Design: 16 px/thread (wave covers 4KB contiguous per plane), depth-2
//     explicit load pipeline, online softmax-max (each value consumed once),
//     64-replica LDS bins (slot=bin*64+lane: zero intra-wave contention, 2-way
//     bank aliasing = free), per-block partial stores (separate conf/cnt/corr
//     arrays -> no packing overflow in global path), tiny reduce kernel.

constexpr int NBINS = 15;
constexpr int NC    = 19;      // classes (fixed by reference)
constexpr int HWSH  = 19;      // H*W = 512*1024 = 2^19 (fixed by reference)

typedef float f32x4 __attribute__((ext_vector_type(4)));
typedef int   i32x4 __attribute__((ext_vector_type(4)));

__global__ __launch_bounds__(256) void ece_partial_kernel(
    const float* __restrict__ logits,
    const int*   __restrict__ labels,
    float*        __restrict__ p_conf,   // [nb*NBINS] per-block conf sums
    unsigned int* __restrict__ p_cnt,    // [nb*NBINS] per-block counts
    unsigned int* __restrict__ p_corr,   // [nb*NBINS] per-block correct counts
    int P16)                             // number of 16-pixel super-groups
{
    __shared__ unsigned s_mc[NBINS * 64];   // (cnt<<16)|corr per (bin, lane-replica)
    __shared__ float    s_cf[NBINS * 64];   // conf sum per (bin, lane-replica)

    const int t = threadIdx.x;
    for (int i = t; i < NBINS * 64; i += 256) { s_mc[i] = 0u; s_cf[i] = 0.0f; }
    __syncthreads();

    const int lane   = t & 63;
    const int HW     = 1 << HWSH;
    const int stride = gridDim.x * 256;

    for (int G = blockIdx.x * 256 + t; G < P16; G += stride) {
        const int p   = G << 4;              // first of this thread's 16 pixels
        const int n   = p >> HWSH;
        const int rem = p & (HW - 1);        // 16-aligned; rem+15 stays in-plane
        const float* base = logits + (((size_t)(n * NC)) << HWSH) + rem;

        i32x4 lab[4];
        #pragma unroll
        for (int k = 0; k < 4; ++k)
            lab[k] = *reinterpret_cast<const i32x4*>(labels + p + 4 * k);

        // ---- online softmax-max, depth-2 explicit load pipeline ----
        float m[16], s[16];
        int   am[16];

        f32x4 cur[4], nxt[4];
        #pragma unroll
        for (int k = 0; k < 4; ++k)
            cur[k] = *reinterpret_cast<const f32x4*>(base + 4 * k);                  // class 0
        #pragma unroll
        for (int k = 0; k < 4; ++k)
            nxt[k] = *reinterpret_cast<const f32x4*>(base + (1ull << HWSH) + 4 * k); // class 1

        #pragma unroll
        for (int k = 0; k < 4; ++k)
            #pragma unroll
            for (int j = 0; j < 4; ++j) {
                m[4 * k + j] = cur[k][j]; s[4 * k + j] = 1.0f; am[4 * k + j] = 0;
            }

        #pragma unroll
        for (int c = 1; c < NC; ++c) {
            f32x4 fut[4];
            if (c + 1 < NC) {                 // folds at compile time (full unroll)
                const float* bc = base + ((size_t)(c + 1) << HWSH);
                #pragma unroll
                for (int k = 0; k < 4; ++k)
                    fut[k] = *reinterpret_cast<const f32x4*>(bc + 4 * k);
            }
            #pragma unroll
            for (int k = 0; k < 4; ++k) {
                #pragma unroll
                for (int j = 0; j < 4; ++j) {
                    const int   i  = 4 * k + j;
                    const float vj = nxt[k][j];                  // class c's value
                    const bool  gt = vj > m[i];                  // strict > = first max
                    const float e  = __expf(-fabsf(vj - m[i]));  // exp(m-v) or exp(v-m)
                    s[i]  = gt ? s[i] * e + 1.0f : s[i] + e;
                    am[i] = gt ? c : am[i];
                    m[i]  = gt ? vj : m[i];
                }
            }
            if (c + 1 < NC) {
                #pragma unroll
                for (int k = 0; k < 4; ++k) nxt[k] = fut[k];
            }
        }

        #pragma unroll
        for (int k = 0; k < 4; ++k) {
            #pragma unroll
            for (int j = 0; j < 4; ++j) {
                const int   i    = 4 * k + j;
                const float conf = 1.0f / s[i];
                int b = (int)ceilf(conf * 15.0f) - 1;            // (lo,hi] bins
                b = b < 0 ? 0 : (b > NBINS - 1 ? NBINS - 1 : b);
                const int idx = b * 64 + lane;
                atomicAdd(&s_mc[idx], 0x10000u | (unsigned)(am[i] == lab[k][j]));
                atomicAdd(&s_cf[idx], conf);
            }
        }
    }
    __syncthreads();

    // Block reduction -> plain partial stores (no global atomics, no memset dep).
    if (t < NBINS) {
        unsigned cnt = 0u, cor = 0u;
        float    cf = 0.0f;
        #pragma unroll 4
        for (int r = 0; r < 64; ++r) {
            const unsigned mc = s_mc[t * 64 + r];
            cnt += mc >> 16; cor += mc & 0xFFFFu;
            cf  += s_cf[t * 64 + r];
        }
        const int o = blockIdx.x * NBINS + t;
        p_conf[o] = cf; p_cnt[o] = cnt; p_corr[o] = cor;
    }
}

__global__ void ece_final_kernel(const float* __restrict__ p_conf,
                                 const unsigned int* __restrict__ p_cnt,
                                 const unsigned int* __restrict__ p_corr,
                                 float* __restrict__ out, int nb, float total)
{
    __shared__ double   sc  [NBINS][16];
    __shared__ unsigned scnt[NBINS][16];
    __shared__ unsigned scor[NBINS][16];
    const int t = threadIdx.x;
    if (t < NBINS * 16) {
        const int bin = t >> 4, sub = t & 15;
        double   cf = 0.0;
        unsigned cnt = 0u, cor = 0u;
        for (int i = sub; i < nb; i += 16) {
            cf  += (double)p_conf[i * NBINS + bin];
            cnt += p_cnt [i * NBINS + bin];
            cor += p_corr[i * NBINS + bin];
        }
        sc[bin][sub] = cf; scnt[bin][sub] = cnt; scor[bin][sub] = cor;
    }
    __syncthreads();
    if (t == 0) {
        double e = 0.0;
        for (int b = 0; b < NBINS; ++b) {
            double   cf = 0.0;
            unsigned cnt = 0u, cor = 0u;
            for (int r = 0; r < 16; ++r) { cf += sc[b][r]; cnt += scnt[b][r]; cor += scor[b][r]; }
            if (cnt) {
                const double c = (double)cnt;
                e += fabs(cf / c - (double)cor / c) * (c / (double)total);
            }
        }
        out[0] = (float)e;
    }
}

extern "C" void kernel_launch(void* const* d_in, const int* in_sizes, int n_in,
                              void* d_out, int out_size, void* d_ws, size_t ws_size,
                              hipStream_t stream) {
    const float* logits = (const float*)d_in[0];
    const int*   labels = (const int*)d_in[1];   // harness converts integer inputs to int32
    float*       out    = (float*)d_out;

    const int P   = in_sizes[1];   // 8*512*1024 = 4,194,304 pixels (divisible by 16)
    const int P16 = P >> 4;

    int nb = (P16 + 255) / 256;                        // 1024 for this shape
    const int nb_ws = (int)(ws_size / (NBINS * 12));   // 12B per (block,bin)
    if (nb > nb_ws) nb = nb_ws;
    if (nb < 1) nb = 1;

    float*        p_conf = (float*)d_ws;
    unsigned int* p_cnt  = (unsigned int*)((char*)d_ws + (size_t)nb * NBINS * 4);
    unsigned int* p_corr = (unsigned int*)((char*)d_ws + (size_t)nb * NBINS * 8);

    ece_partial_kernel<<<nb, 256, 0, stream>>>(logits, labels, p_conf, p_cnt, p_corr, P16);
    ece_final_kernel<<<1, 256, 0, stream>>>(p_conf, p_cnt, p_corr, out, nb, (float)P);
}

// Round 7
// 86.876 us; speedup vs baseline: 1.3684x; 1.3684x over previous
//
#include <hip/hip_runtime.h>
#include <hip/hip_bf16.h>

// ECE over logits (8,19,512,1024) f32, labels (8,512,1024) int32.
// R7 = best measured pieces recombined:
//   core: R1's two-pass full v[19][4] register array (all 19 plane loads issued
//         back-to-back -> max MLP; online-softmax variants let the compiler
//         shrink loads-in-flight and regressed), 4 px/thread, 2048 blocks.
//   LDS:  64-replica bins (slot = bin*64+lane): zero intra-wave same-address
//         serialization, bank = lane%32 (2-way aliasing = free), cnt|corr packed
//         -> 2 LDS atomics/pixel (R1 had 8-way serialization x3 atomics).
//   tail: per-block partial stores (no memset dispatch, no global atomics) +
//         one wide 1024-thread finalize kernel. 2 dispatches total.

constexpr int NBINS = 15;
constexpr int NC    = 19;      // classes (fixed by reference)
constexpr int HWSH  = 19;      // H*W = 512*1024 = 2^19 (fixed by reference)

typedef float f32x4 __attribute__((ext_vector_type(4)));
typedef int   i32x4 __attribute__((ext_vector_type(4)));

__global__ __launch_bounds__(256) void ece_partial_kernel(
    const float* __restrict__ logits,
    const int*   __restrict__ labels,
    float*        __restrict__ p_conf,   // [nb*NBINS] per-block conf sums
    unsigned int* __restrict__ p_cnt,    // [nb*NBINS] per-block counts
    unsigned int* __restrict__ p_corr,   // [nb*NBINS] per-block correct counts
    int P4)                              // number of 4-pixel groups
{
    __shared__ unsigned s_mc[NBINS * 64];   // (cnt<<16)|corr per (bin, lane-replica)
    __shared__ float    s_cf[NBINS * 64];   // conf sum per (bin, lane-replica)

    const int t = threadIdx.x;
    for (int i = t; i < NBINS * 64; i += 256) { s_mc[i] = 0u; s_cf[i] = 0.0f; }
    __syncthreads();

    const int lane   = t & 63;
    const int HW     = 1 << HWSH;
    const int stride = gridDim.x * 256;

    for (int g = blockIdx.x * 256 + t; g < P4; g += stride) {
        const int p   = g << 2;              // first pixel of this 4-group
        const int n   = p >> HWSH;           // image index
        const int rem = p & (HW - 1);        // h*W + w within the image
        const float* base = logits + (((size_t)(n * NC)) << HWSH) + rem;

        // Load ALL 19 class values for 4 consecutive pixels (coalesced 16B/lane,
        // wave covers 1KB contiguous per plane; 19 loads in flight = MLP).
        float v[NC][4];
        #pragma unroll
        for (int c = 0; c < NC; ++c) {
            const f32x4 x = *reinterpret_cast<const f32x4*>(base + ((size_t)c << HWSH));
            v[c][0] = x[0]; v[c][1] = x[1]; v[c][2] = x[2]; v[c][3] = x[3];
        }
        const i32x4 lab = *reinterpret_cast<const i32x4*>(labels + p);

        #pragma unroll
        for (int j = 0; j < 4; ++j) {
            float mx = v[0][j];
            int   am = 0;
            #pragma unroll
            for (int c = 1; c < NC; ++c)
                if (v[c][j] > mx) { mx = v[c][j]; am = c; }   // strict > = first max (jnp)
            float s = 0.0f;
            #pragma unroll
            for (int c = 0; c < NC; ++c) s += __expf(v[c][j] - mx);
            const float conf = 1.0f / s;

            int b = (int)ceilf(conf * 15.0f) - 1;             // (lo,hi] bins
            b = b < 0 ? 0 : (b > NBINS - 1 ? NBINS - 1 : b);
            const int idx = b * 64 + lane;
            atomicAdd(&s_mc[idx], 0x10000u | (unsigned)(am == lab[j]));
            atomicAdd(&s_cf[idx], conf);
        }
    }
    __syncthreads();

    // Block reduction -> plain partial stores. Pixels per (bin,lane) slot is
    // bounded by 4 threads * 4 px * iters; iters <= 32 for any nb >= 64, so
    // (cnt<<16) cannot overflow and corr never carries into cnt.
    if (t < NBINS) {
        unsigned cnt = 0u, cor = 0u;
        float    cf = 0.0f;
        #pragma unroll 4
        for (int r = 0; r < 64; ++r) {
            const unsigned mc = s_mc[t * 64 + r];
            cnt += mc >> 16; cor += mc & 0xFFFFu;
            cf  += s_cf[t * 64 + r];
        }
        const int o = blockIdx.x * NBINS + t;
        p_conf[o] = cf; p_cnt[o] = cnt; p_corr[o] = cor;
    }
}

__global__ __launch_bounds__(1024) void ece_final_kernel(
    const float* __restrict__ p_conf,
    const unsigned int* __restrict__ p_cnt,
    const unsigned int* __restrict__ p_corr,
    float* __restrict__ out, int nb, float total)
{
    __shared__ double   sc  [NBINS * 64];
    __shared__ unsigned scnt[NBINS * 64];
    __shared__ unsigned scor[NBINS * 64];
    __shared__ double   gaps[NBINS];

    const int t   = threadIdx.x;       // 1024 threads; bins use 960
    const int bin = t >> 6;
    const int sub = t & 63;

    if (bin < NBINS) {
        double   cf = 0.0;
        unsigned cnt = 0u, cor = 0u;
        for (int i = sub; i < nb; i += 64) {
            cf  += (double)p_conf[i * NBINS + bin];
            cnt += p_cnt [i * NBINS + bin];
            cor += p_corr[i * NBINS + bin];
        }
        sc[t] = cf; scnt[t] = cnt; scor[t] = cor;
    }
    __syncthreads();

    // fold 64 -> 8 (stride-8 read set: thread `sub` reads {sub, sub+8, ...},
    // writes slot `sub` -- write slots {0..7} only appear in their own reader).
    if (bin < NBINS && sub < 8) {
        double   c2 = 0.0;
        unsigned n2 = 0u, r2 = 0u;
        for (int r = sub; r < 64; r += 8) {
            c2 += sc[bin * 64 + r]; n2 += scnt[bin * 64 + r]; r2 += scor[bin * 64 + r];
        }
        sc[bin * 64 + sub] = c2; scnt[bin * 64 + sub] = n2; scor[bin * 64 + sub] = r2;
    }
    __syncthreads();

    if (t < NBINS) {
        double   c3 = 0.0;
        unsigned n3 = 0u, r3 = 0u;
        for (int r = 0; r < 8; ++r) {
            c3 += sc[t * 64 + r]; n3 += scnt[t * 64 + r]; r3 += scor[t * 64 + r];
        }
        gaps[t] = n3 ? fabs(c3 / (double)n3 - (double)r3 / (double)n3)
                         * ((double)n3 / (double)total)
                     : 0.0;
    }
    __syncthreads();

    if (t == 0) {
        double e = 0.0;
        for (int b = 0; b < NBINS; ++b) e += gaps[b];
        out[0] = (float)e;
    }
}

extern "C" void kernel_launch(void* const* d_in, const int* in_sizes, int n_in,
                              void* d_out, int out_size, void* d_ws, size_t ws_size,
                              hipStream_t stream) {
    const float* logits = (const float*)d_in[0];
    const int*   labels = (const int*)d_in[1];   // harness converts integer inputs to int32
    float*       out    = (float*)d_out;

    const int P  = in_sizes[1];   // 8*512*1024 = 4,194,304 pixels
    const int P4 = P >> 2;

    int nb = (P4 + 255) / 256;                         // 4096 for this shape
    if (nb > 2048) nb = 2048;                          // R1's proven config: 2 iters/thread
    const int nb_ws = (int)(ws_size / (NBINS * 12));   // 12B per (block,bin)
    if (nb > nb_ws) nb = nb_ws;
    if (nb < 1) nb = 1;

    float*        p_conf = (float*)d_ws;
    unsigned int* p_cnt  = (unsigned int*)((char*)d_ws + (size_t)nb * NBINS * 4);
    unsigned int* p_corr = (unsigned int*)((char*)d_ws + (size_t)nb * NBINS * 8);

    ece_partial_kernel<<<nb, 256, 0, stream>>>(logits, labels, p_conf, p_cnt, p_corr, P4);
    ece_final_kernel<<<1, 1024, 0, stream>>>(p_conf, p_cnt, p_corr, out, nb, (float)P);
}

// Round 8
// 86.018 us; speedup vs baseline: 1.3821x; 1.0100x over previous
//
#include <hip/hip_runtime.h>
#include <hip/hip_bf16.h>

// ECE over logits (8,19,512,1024) f32, labels (8,512,1024) int32.
// R8: class-outer tiled streaming. Evidence: R1/R4/R7 plateau at 81-91us with
//     VALUBusy ~6%, occupancy ~45%, L3-resident == HBM-fed speed -> limiter is
//     the DRAM access SHAPE (19 x 1KB strided chunks per wave), not atomics/
//     LDS/tails. Here each block owns a contiguous 4096-px tile and streams
//     each class plane as one 16KB contiguous read (4 dwordx4/thread, loads
//     independent across classes -> freely pipelined). Per-pixel online-softmax
//     state (m,s,am x16) in registers, statically indexed. Labels loaded after
//     the class loop. 64-replica LDS bins, partial stores, wide finalize.

constexpr int NBINS = 15;
constexpr int NC    = 19;      // classes (fixed by reference)
constexpr int HWSH  = 19;      // H*W = 512*1024 = 2^19 (fixed by reference)
constexpr int TILE  = 4096;    // pixels per block-tile (divides 2^19)

typedef float f32x4 __attribute__((ext_vector_type(4)));
typedef int   i32x4 __attribute__((ext_vector_type(4)));

__global__ __launch_bounds__(256) void ece_partial_kernel(
    const float* __restrict__ logits,
    const int*   __restrict__ labels,
    float*        __restrict__ p_conf,   // [nb*NBINS] per-block conf sums
    unsigned int* __restrict__ p_cnt,    // [nb*NBINS] per-block counts
    unsigned int* __restrict__ p_corr,   // [nb*NBINS] per-block correct counts
    int ntiles)
{
    __shared__ unsigned s_mc[NBINS * 64];   // (cnt<<16)|corr per (bin, lane-replica)
    __shared__ float    s_cf[NBINS * 64];   // conf sum per (bin, lane-replica)

    const int t = threadIdx.x;
    for (int i = t; i < NBINS * 64; i += 256) { s_mc[i] = 0u; s_cf[i] = 0.0f; }
    __syncthreads();

    const int lane = t & 63;
    const int HW   = 1 << HWSH;

    for (int tile = blockIdx.x; tile < ntiles; tile += gridDim.x) {
        const int p0  = tile * TILE;         // tile base pixel (TILE divides HW)
        const int n   = p0 >> HWSH;
        const int rem = p0 & (HW - 1);
        const float* ibase = logits + (((size_t)(n * NC)) << HWSH) + rem;

        // Thread handles 16 px: tile offsets k*1024 + t*4 + {0..3}, k=0..3.
        // Per class the whole block reads [p0, p0+4096) = 16KB contiguous.
        float m[16], s[16];
        int   am[16];

        // ---- class 0: init state ----
        #pragma unroll
        for (int k = 0; k < 4; ++k) {
            const f32x4 x = *reinterpret_cast<const f32x4*>(ibase + k * 1024 + t * 4);
            #pragma unroll
            for (int j = 0; j < 4; ++j) {
                m[4 * k + j] = x[j]; s[4 * k + j] = 1.0f; am[4 * k + j] = 0;
            }
        }

        // ---- classes 1..18: online softmax-max, loads independent across c ----
        #pragma unroll
        for (int c = 1; c < NC; ++c) {
            const float* bc = ibase + ((size_t)c << HWSH);
            f32x4 x[4];
            #pragma unroll
            for (int k = 0; k < 4; ++k)
                x[k] = *reinterpret_cast<const f32x4*>(bc + k * 1024 + t * 4);
            #pragma unroll
            for (int k = 0; k < 4; ++k) {
                #pragma unroll
                for (int j = 0; j < 4; ++j) {
                    const int   i  = 4 * k + j;
                    const float vj = x[k][j];
                    const bool  gt = vj > m[i];                  // strict > = first max (jnp)
                    const float e  = __expf(-fabsf(vj - m[i]));  // exp(m-v) or exp(v-m)
                    s[i]  = gt ? s[i] * e + 1.0f : s[i] + e;
                    am[i] = gt ? c : am[i];
                    m[i]  = gt ? vj : m[i];
                }
            }
        }

        // ---- labels + binning (labels not live during class loop) ----
        #pragma unroll
        for (int k = 0; k < 4; ++k) {
            const i32x4 lab = *reinterpret_cast<const i32x4*>(labels + p0 + k * 1024 + t * 4);
            #pragma unroll
            for (int j = 0; j < 4; ++j) {
                const int   i    = 4 * k + j;
                const float conf = 1.0f / s[i];
                int b = (int)ceilf(conf * 15.0f) - 1;            // (lo,hi] bins
                b = b < 0 ? 0 : (b > NBINS - 1 ? NBINS - 1 : b);
                const int idx = b * 64 + lane;
                atomicAdd(&s_mc[idx], 0x10000u | (unsigned)(am[i] == lab[j]));
                atomicAdd(&s_cf[idx], conf);
            }
        }
    }
    __syncthreads();

    // Block reduction -> partial stores. Max count per (bin,lane) slot:
    // 4 waves * 16 px * tiles-per-block (<=4 here) = 256 << 65535: packing safe.
    if (t < NBINS) {
        unsigned cnt = 0u, cor = 0u;
        float    cf = 0.0f;
        #pragma unroll 4
        for (int r = 0; r < 64; ++r) {
            const unsigned mc = s_mc[t * 64 + r];
            cnt += mc >> 16; cor += mc & 0xFFFFu;
            cf  += s_cf[t * 64 + r];
        }
        const int o = blockIdx.x * NBINS + t;
        p_conf[o] = cf; p_cnt[o] = cnt; p_corr[o] = cor;
    }
}

__global__ __launch_bounds__(1024) void ece_final_kernel(
    const float* __restrict__ p_conf,
    const unsigned int* __restrict__ p_cnt,
    const unsigned int* __restrict__ p_corr,
    float* __restrict__ out, int nb, float total)
{
    __shared__ double   sc  [NBINS * 64];
    __shared__ unsigned scnt[NBINS * 64];
    __shared__ unsigned scor[NBINS * 64];
    __shared__ double   gaps[NBINS];

    const int t   = threadIdx.x;       // 1024 threads; bins use 960
    const int bin = t >> 6;
    const int sub = t & 63;

    if (bin < NBINS) {
        double   cf = 0.0;
        unsigned cnt = 0u, cor = 0u;
        for (int i = sub; i < nb; i += 64) {
            cf  += (double)p_conf[i * NBINS + bin];
            cnt += p_cnt [i * NBINS + bin];
            cor += p_corr[i * NBINS + bin];
        }
        sc[t] = cf; scnt[t] = cnt; scor[t] = cor;
    }
    __syncthreads();

    if (bin < NBINS && sub < 8) {      // fold 64 -> 8 (disjoint stride-8 sets)
        double   c2 = 0.0;
        unsigned n2 = 0u, r2 = 0u;
        for (int r = sub; r < 64; r += 8) {
            c2 += sc[bin * 64 + r]; n2 += scnt[bin * 64 + r]; r2 += scor[bin * 64 + r];
        }
        sc[bin * 64 + sub] = c2; scnt[bin * 64 + sub] = n2; scor[bin * 64 + sub] = r2;
    }
    __syncthreads();

    if (t < NBINS) {
        double   c3 = 0.0;
        unsigned n3 = 0u, r3 = 0u;
        for (int r = 0; r < 8; ++r) {
            c3 += sc[t * 64 + r]; n3 += scnt[t * 64 + r]; r3 += scor[t * 64 + r];
        }
        gaps[t] = n3 ? fabs(c3 / (double)n3 - (double)r3 / (double)n3)
                         * ((double)n3 / (double)total)
                     : 0.0;
    }
    __syncthreads();

    if (t == 0) {
        double e = 0.0;
        for (int b = 0; b < NBINS; ++b) e += gaps[b];
        out[0] = (float)e;
    }
}

extern "C" void kernel_launch(void* const* d_in, const int* in_sizes, int n_in,
                              void* d_out, int out_size, void* d_ws, size_t ws_size,
                              hipStream_t stream) {
    const float* logits = (const float*)d_in[0];
    const int*   labels = (const int*)d_in[1];   // harness converts integer inputs to int32
    float*       out    = (float*)d_out;

    const int P      = in_sizes[1];   // 8*512*1024 = 4,194,304 pixels
    const int ntiles = P / TILE;      // 1024 for this shape

    int nb = ntiles;                                   // 1 tile per block: 4 blocks/CU
    const int nb_ws = (int)(ws_size / (NBINS * 12));   // 12B per (block,bin)
    if (nb > nb_ws) nb = nb_ws;                        // grid-stride handles nb < ntiles
    if (nb < 1) nb = 1;

    float*        p_conf = (float*)d_ws;
    unsigned int* p_cnt  = (unsigned int*)((char*)d_ws + (size_t)nb * NBINS * 4);
    unsigned int* p_corr = (unsigned int*)((char*)d_ws + (size_t)nb * NBINS * 8);

    ece_partial_kernel<<<nb, 256, 0, stream>>>(logits, labels, p_conf, p_cnt, p_corr, ntiles);
    ece_final_kernel<<<1, 1024, 0, stream>>>(p_conf, p_cnt, p_corr, out, nb, (float)P);
}

// Round 9
// 70.198 us; speedup vs baseline: 1.6935x; 1.2254x over previous
//
#include <hip/hip_runtime.h>
#include <hip/hip_bf16.h>

// ECE over logits (8,19,512,1024) f32, labels (8,512,1024) int32.
// R9: occupancy push on the proven R1 two-pass core.
//   Evidence: 4 structural variants (pixel-inner, online, class-outer tiles)
//   all plateau at 78-80us partial (4.3 TB/s, VALUBusy ~6%, occ 42%) -> not
//   shape-, atomic-, or compute-bound; last unfalsified theory = concurrency.
//   Changes: (a) uint32 element offsets from uniform base -> saddr-form loads,
//   ~90 VGPR instead of ~128; (b) __launch_bounds__(256,5) -> 5 waves/SIMD
//   (62% occ, +47% in-flight); (c) nb=512 partial stores + 960-wide finalize.

constexpr int NBINS = 15;
constexpr int NC    = 19;      // classes (fixed by reference)
constexpr int HWSH  = 19;      // H*W = 512*1024 = 2^19 (fixed by reference)

typedef float f32x4 __attribute__((ext_vector_type(4)));
typedef int   i32x4 __attribute__((ext_vector_type(4)));

__global__ __launch_bounds__(256, 5) void ece_partial_kernel(
    const float* __restrict__ logits,
    const int*   __restrict__ labels,
    float*        __restrict__ p_conf,   // [nb*NBINS] per-block conf sums
    unsigned int* __restrict__ p_cnt,    // [nb*NBINS] per-block counts
    unsigned int* __restrict__ p_corr,   // [nb*NBINS] per-block correct counts
    int P4)                              // number of 4-pixel groups
{
    __shared__ unsigned s_mc[NBINS * 64];   // (cnt<<16)|corr per (bin, lane-replica)
    __shared__ float    s_cf[NBINS * 64];   // conf sum per (bin, lane-replica)

    const int t = threadIdx.x;
    for (int i = t; i < NBINS * 64; i += 256) { s_mc[i] = 0u; s_cf[i] = 0.0f; }
    __syncthreads();

    const int lane   = t & 63;
    const unsigned HW = 1u << HWSH;
    const int stride = gridDim.x * 256;

    for (int g = blockIdx.x * 256 + t; g < P4; g += stride) {
        const unsigned p   = (unsigned)g << 2;        // first pixel of this 4-group
        const unsigned n   = p >> HWSH;               // image index
        const unsigned rem = p & (HW - 1);            // h*W + w within the image
        // uint32 ELEMENT offset from the uniform logits base: max (8*19)<<19 < 2^31.
        // Keeps loads in saddr form (SGPR base + 32-bit voffset) -> low VGPR.
        const unsigned base = (n * NC) << HWSH | rem;

        // Load ALL 19 class values for 4 consecutive pixels (burst of 19
        // independent dwordx4 + 1 label load -> max loads-in-flight).
        f32x4 v[NC];
        #pragma unroll
        for (int c = 0; c < NC; ++c)
            v[c] = *reinterpret_cast<const f32x4*>(logits + (base + ((unsigned)c << HWSH)));
        const i32x4 lab = *reinterpret_cast<const i32x4*>(labels + p);

        #pragma unroll
        for (int j = 0; j < 4; ++j) {
            float mx = v[0][j];
            int   am = 0;
            #pragma unroll
            for (int c = 1; c < NC; ++c)
                if (v[c][j] > mx) { mx = v[c][j]; am = c; }   // strict > = first max (jnp)
            float s = 0.0f;
            #pragma unroll
            for (int c = 0; c < NC; ++c) s += __expf(v[c][j] - mx);
            const float conf = 1.0f / s;

            int b = (int)ceilf(conf * 15.0f) - 1;             // (lo,hi] bins
            b = b < 0 ? 0 : (b > NBINS - 1 ? NBINS - 1 : b);
            const int idx = b * 64 + lane;
            atomicAdd(&s_mc[idx], 0x10000u | (unsigned)(am == lab[j]));
            atomicAdd(&s_cf[idx], conf);
        }
    }
    __syncthreads();

    // Block reduction -> partial stores. Per (bin,lane) slot: 4 threads share a
    // lane, each does <=8 iters * 4 px -> cnt <= 128 << 65535: packing safe.
    if (t < NBINS) {
        unsigned cnt = 0u, cor = 0u;
        float    cf = 0.0f;
        #pragma unroll 4
        for (int r = 0; r < 64; ++r) {
            const unsigned mc = s_mc[t * 64 + r];
            cnt += mc >> 16; cor += mc & 0xFFFFu;
            cf  += s_cf[t * 64 + r];
        }
        const int o = blockIdx.x * NBINS + t;
        p_conf[o] = cf; p_cnt[o] = cnt; p_corr[o] = cor;
    }
}

__global__ __launch_bounds__(1024) void ece_final_kernel(
    const float* __restrict__ p_conf,
    const unsigned int* __restrict__ p_cnt,
    const unsigned int* __restrict__ p_corr,
    float* __restrict__ out, int nb, float total)
{
    __shared__ double   sc  [NBINS * 64];
    __shared__ unsigned scnt[NBINS * 64];
    __shared__ unsigned scor[NBINS * 64];
    __shared__ double   gaps[NBINS];

    const int t   = threadIdx.x;       // 1024 threads; bins use 960
    const int bin = t >> 6;
    const int sub = t & 63;

    if (bin < NBINS) {
        double   cf = 0.0;
        unsigned cnt = 0u, cor = 0u;
        for (int i = sub; i < nb; i += 64) {
            cf  += (double)p_conf[i * NBINS + bin];
            cnt += p_cnt [i * NBINS + bin];
            cor += p_corr[i * NBINS + bin];
        }
        sc[t] = cf; scnt[t] = cnt; scor[t] = cor;
    }
    __syncthreads();

    if (bin < NBINS && sub < 8) {      // fold 64 -> 8 (disjoint stride-8 sets)
        double   c2 = 0.0;
        unsigned n2 = 0u, r2 = 0u;
        for (int r = sub; r < 64; r += 8) {
            c2 += sc[bin * 64 + r]; n2 += scnt[bin * 64 + r]; r2 += scor[bin * 64 + r];
        }
        sc[bin * 64 + sub] = c2; scnt[bin * 64 + sub] = n2; scor[bin * 64 + sub] = r2;
    }
    __syncthreads();

    if (t < NBINS) {
        double   c3 = 0.0;
        unsigned n3 = 0u, r3 = 0u;
        for (int r = 0; r < 8; ++r) {
            c3 += sc[t * 64 + r]; n3 += scnt[t * 64 + r]; r3 += scor[t * 64 + r];
        }
        gaps[t] = n3 ? fabs(c3 / (double)n3 - (double)r3 / (double)n3)
                         * ((double)n3 / (double)total)
                     : 0.0;
    }
    __syncthreads();

    if (t == 0) {
        double e = 0.0;
        for (int b = 0; b < NBINS; ++b) e += gaps[b];
        out[0] = (float)e;
    }
}

extern "C" void kernel_launch(void* const* d_in, const int* in_sizes, int n_in,
                              void* d_out, int out_size, void* d_ws, size_t ws_size,
                              hipStream_t stream) {
    const float* logits = (const float*)d_in[0];
    const int*   labels = (const int*)d_in[1];   // harness converts integer inputs to int32
    float*       out    = (float*)d_out;

    const int P  = in_sizes[1];   // 8*512*1024 = 4,194,304 pixels
    const int P4 = P >> 2;

    int nb = 512;                                      // grid-stride (8 iters/thread);
    const int nb_ws = (int)(ws_size / (NBINS * 12));   // resident occupancy unaffected,
    if (nb > nb_ws) nb = nb_ws;                        // finalize reads 4x less than nb=2048
    if (nb < 1) nb = 1;

    float*        p_conf = (float*)d_ws;
    unsigned int* p_cnt  = (unsigned int*)((char*)d_ws + (size_t)nb * NBINS * 4);
    unsigned int* p_corr = (unsigned int*)((char*)d_ws + (size_t)nb * NBINS * 8);

    ece_partial_kernel<<<nb, 256, 0, stream>>>(logits, labels, p_conf, p_cnt, p_corr, P4);
    ece_final_kernel<<<1, 1024, 0, stream>>>(p_conf, p_cnt, p_corr, out, nb, (float)P);
}